// Round 1
// baseline (228.001 us; speedup 1.0000x reference)
//
#include <hip/hip_runtime.h>

#define S_DIM 26
#define NCLS 80
#define CELLS 676        // 26*26
#define NB 32
#define NCH 255          // 3*(5+80)
#define NPLANE 2028      // 3*676
#define CH_BLK 85        // 5+80

__global__ __launch_bounds__(256)
void yolo_loss_kernel(const float* __restrict__ x,     // (B,255,26,26)
                      const float* __restrict__ box,   // (B,32,5)
                      const int*   __restrict__ nidx,  // (B,32)
                      float* __restrict__ out)
{
    const int b   = blockIdx.x;
    const int tid = threadIdx.x;
    const float* xb = x + (size_t)b * (NCH * CELLS);

    __shared__ int   s_key[NB];    // now_index*676 + cell  (for dedupe)
    __shared__ int   s_off[NB];    // base*676 + cell       (address offset)
    __shared__ int   s_cls[NB];
    __shared__ float s_obj2[NB];   // x[base,ix,iy]^2
    __shared__ float s_part[4][4]; // 4 accumulators x 4 waves

    float accA = 0.f;  // scalar mse terms (unscaled sum over boxes)
    float accL = 0.f;  // label term sum
    float accP = 0.f;  // 3-plane sum of squares
    float accD = 0.f;  // dedupe correction (sum of obj^2 over distinct triples)
    float accC = 0.f;  // distinct triple count

    // ---- Phase 1: per-box head math (threads 0..31) ----
    if (tid < NB) {
        const float* bx = box + ((size_t)b * NB + tid) * 5;
        float cls = bx[0], cx = bx[1], cy = bx[2], w = bx[3], h = bx[4];
        int n  = nidx[b * NB + tid];       // in [3,5]
        int ni = n - 3;                    // 0..2
        int ix = (int)(cx * (1.0f / 16.0f));
        int iy = (int)(cy * (1.0f / 16.0f));
        float ax = (cx - (float)ix * 16.0f) * (1.0f / 16.0f);
        float ay = (cy - (float)iy * 16.0f) * (1.0f / 16.0f);
        int cell = ix * S_DIM + iy;
        int off  = ni * CH_BLK * CELLS + cell;

        s_key[tid] = ni * CELLS + cell;
        s_off[tid] = off;
        s_cls[tid] = (int)cls;

        float obj = xb[off];
        float rax = xb[off + 1 * CELLS];
        float ray = xb[off + 2 * CELLS];
        float t3  = xb[off + 3 * CELLS];
        float t4  = xb[off + 4 * CELLS];
        s_obj2[tid] = obj * obj;

        // anchors rows 3..5: (30,61) (62,45) (59,119)
        const float AW[3] = {30.f, 62.f, 59.f};
        const float AH[3] = {61.f, 45.f, 119.f};
        float sig3 = 1.0f / (1.0f + expf(-t3));
        float sig4 = 1.0f / (1.0f + expf(-t4));
        float rw = AW[ni] * expf(4.0f * sig3 - 2.0f);
        float rh = AH[ni] * expf(4.0f * sig4 - 2.0f);

        // IoU (with the +1 convention of the reference)
        float b1x0 = rax * 16.f - rw * 0.5f, b1y0 = ray * 16.f - rh * 0.5f;
        float b1x1 = rax * 16.f + rw * 0.5f, b1y1 = ray * 16.f + rh * 0.5f;
        float b2x0 = ax * 16.f - w * 0.5f,   b2y0 = ay * 16.f - h * 0.5f;
        float b2x1 = ax * 16.f + w * 0.5f,   b2y1 = ay * 16.f + h * 0.5f;
        float A  = (rw + 1.f) * (rh + 1.f);
        float Bt = (w + 1.f) * (h + 1.f);
        float CM = (fminf(b1x1, b2x1) - fmaxf(b1x0, b2x0) + 1.f) *
                   (fminf(b1y1, b2y1) - fmaxf(b1y0, b2y0) + 1.f);
        float r = CM / (A + Bt - CM);
        float iou = (r < 0.f) ? 0.f : r;

        float d;
        d = obj - iou;                  accA += d * d;
        d = rax - ax;                   accA += d * d;
        d = ray - ay;                   accA += d * d;
        d = (rw - w) * (1.f / 416.f);   accA += d * d;
        d = (rh - h) * (1.f / 416.f);   accA += d * d;
    }
    __syncthreads();

    // ---- Phase 2: dedupe for noobj mask correction ----
    if (tid < NB) {
        int key = s_key[tid];
        bool first = true;
        for (int s = 0; s < tid; ++s)
            if (s_key[s] == key) { first = false; break; }
        if (first) { accC += 1.0f; accD += s_obj2[tid]; }
    }

    // ---- Phase 3: label (class) mse term, 32*80 = 2560 elems ----
    for (int u = tid; u < NB * NCLS; u += 256) {
        int t = u / NCLS;
        int c = u - t * NCLS;
        float val = xb[s_off[t] + (5 + c) * CELLS];
        float hot = (c == s_cls[t]) ? 1.0f : 0.0f;
        float d = val - hot;
        accL += d * d;
    }

    // ---- Phase 4: noobj plane sum of squares (channels 0,85,170) ----
    for (int u = tid; u < NPLANE; u += 256) {
        int pl   = u / CELLS;          // 0..2
        int cell = u - pl * CELLS;
        float v = xb[pl * CH_BLK * CELLS + cell];
        accP += v * v;
    }

    // ---- Phase 5: block reduction (4 accumulators) ----
    float v1 = accA * (5.0f / 32.0f) + accL * (1.0f / 2560.0f);
    float v2 = accP;
    float v3 = accD;
    float v4 = accC;
    #pragma unroll
    for (int o = 32; o > 0; o >>= 1) {
        v1 += __shfl_down(v1, o, 64);
        v2 += __shfl_down(v2, o, 64);
        v3 += __shfl_down(v3, o, 64);
        v4 += __shfl_down(v4, o, 64);
    }
    int wave = tid >> 6;
    if ((tid & 63) == 0) {
        s_part[0][wave] = v1; s_part[1][wave] = v2;
        s_part[2][wave] = v3; s_part[3][wave] = v4;
    }
    __syncthreads();
    if (tid == 0) {
        float t1 = s_part[0][0] + s_part[0][1] + s_part[0][2] + s_part[0][3];
        float t2 = s_part[1][0] + s_part[1][1] + s_part[1][2] + s_part[1][3];
        float t3 = s_part[2][0] + s_part[2][1] + s_part[2][2] + s_part[2][3];
        float t4 = s_part[3][0] + s_part[3][1] + s_part[3][2] + s_part[3][3];
        float cnt  = 2028.0f - t4;
        float loss = t1 + 0.5f * (t2 - t3) / cnt;
        atomicAdd(out, loss);
    }
}

extern "C" void kernel_launch(void* const* d_in, const int* in_sizes, int n_in,
                              void* d_out, int out_size, void* d_ws, size_t ws_size,
                              hipStream_t stream) {
    const float* x    = (const float*)d_in[0];   // batch_x   (256,255,26,26)
    const float* box  = (const float*)d_in[1];   // batch_box (256,32,5)
    const int*   nidx = (const int*)d_in[2];     // batch_index (256,32)
    float* out = (float*)d_out;

    // d_out is poisoned 0xAA before every timed replay — zero it (capture-safe).
    hipMemsetAsync(out, 0, sizeof(float) * out_size, stream);
    yolo_loss_kernel<<<dim3(256), dim3(256), 0, stream>>>(x, box, nidx, out);
}

// Round 2
// 226.712 us; speedup vs baseline: 1.0057x; 1.0057x over previous
//
#include <hip/hip_runtime.h>

#define S_DIM 26
#define NCLS 80
#define CELLS 676        // 26*26
#define NB 32
#define NCH 255          // 3*(5+80)
#define CH_BLK 85        // 5+80
#define PLANE_F4 507     // 3 * 169
#define F4_PER_PLANE 169 // 676/4
#define F4_PLANE_STRIDE 14365 // 85*676/4

// Per-box head math: returns sum of the 5 squared diffs for this box.
__device__ inline float head_terms(const float* __restrict__ xb,
                                   int off, int ni,
                                   float w, float h, float ax, float ay)
{
    float obj = xb[off];
    float rax = xb[off + 1 * CELLS];
    float ray = xb[off + 2 * CELLS];
    float t3  = xb[off + 3 * CELLS];
    float t4  = xb[off + 4 * CELLS];

    const float AW[3] = {30.f, 62.f, 59.f};   // anchors rows 3..5
    const float AH[3] = {61.f, 45.f, 119.f};
    float sig3 = 1.0f / (1.0f + expf(-t3));
    float sig4 = 1.0f / (1.0f + expf(-t4));
    float rw = AW[ni] * expf(4.0f * sig3 - 2.0f);
    float rh = AH[ni] * expf(4.0f * sig4 - 2.0f);

    float b1x0 = rax * 16.f - rw * 0.5f, b1y0 = ray * 16.f - rh * 0.5f;
    float b1x1 = rax * 16.f + rw * 0.5f, b1y1 = ray * 16.f + rh * 0.5f;
    float b2x0 = ax * 16.f - w * 0.5f,   b2y0 = ay * 16.f - h * 0.5f;
    float b2x1 = ax * 16.f + w * 0.5f,   b2y1 = ay * 16.f + h * 0.5f;
    float A  = (rw + 1.f) * (rh + 1.f);
    float Bt = (w + 1.f) * (h + 1.f);
    float CM = (fminf(b1x1, b2x1) - fmaxf(b1x0, b2x0) + 1.f) *
               (fminf(b1y1, b2y1) - fmaxf(b1y0, b2y0) + 1.f);
    float r = CM / (A + Bt - CM);
    float iou = (r < 0.f) ? 0.f : r;

    float acc = 0.f, d;
    d = obj - iou;                  acc += d * d;
    d = rax - ax;                   acc += d * d;
    d = ray - ay;                   acc += d * d;
    d = (rw - w) * (1.f / 416.f);   acc += d * d;
    d = (rh - h) * (1.f / 416.f);   acc += d * d;
    return acc;
}

__global__ __launch_bounds__(256)
void yolo_loss_kernel(const float* __restrict__ x,     // (B,255,26,26)
                      const float* __restrict__ box,   // (B,32,5)
                      const int*   __restrict__ nidx,  // (B,32)
                      float* __restrict__ out)
{
    const int b     = blockIdx.x;
    const int slice = blockIdx.y;   // 0: boxes 0-15 (+dedupe corr), 1: boxes 16-31, 2: planes
    const int tid   = threadIdx.x;
    const float* xb = x + (size_t)b * (NCH * CELLS);

    __shared__ int   s_key[NB];
    __shared__ int   s_off[NB];
    __shared__ int   s_cls[NB];
    __shared__ float s_obj2[NB];
    __shared__ float s_red[3][4];

    float r0 = 0.f, r1 = 0.f, r2 = 0.f;

    if (slice == 2) {
        // ---- keys for cnt (dedupe count only) ----
        if (tid < NB) {
            const float* bx = box + ((size_t)b * NB + tid) * 5;
            float cx = bx[1], cy = bx[2];
            int ni = nidx[b * NB + tid] - 3;
            int ix = (int)(cx * 0.0625f);
            int iy = (int)(cy * 0.0625f);
            s_key[tid] = ni * CELLS + ix * S_DIM + iy;
        }
        __syncthreads();
        if (tid < NB) {
            bool first = true;
            for (int s = 0; s < tid; ++s)
                if (s_key[s] == s_key[tid]) { first = false; break; }
            if (first) r1 += 1.0f;
        }
        // ---- noobj plane sum of squares, float4 coalesced ----
        const float4* p4 = (const float4*)xb;
        #pragma unroll
        for (int u = tid; u < PLANE_F4; u += 256) {
            int pl = (u >= 2 * F4_PER_PLANE) ? 2 : (u >= F4_PER_PLANE ? 1 : 0);
            int i4 = u - pl * F4_PER_PLANE;
            float4 v = p4[pl * F4_PLANE_STRIDE + i4];
            r0 += v.x * v.x + v.y * v.y + v.z * v.z + v.w * v.w;
        }
    } else {
        const int boxbase = slice * 16;
        const int nboxes_meta = (slice == 0) ? NB : 16;  // slice0 needs all 32 for dedupe
        if (tid < nboxes_meta) {
            int gbox = (slice == 0) ? tid : (boxbase + tid);
            const float* bx = box + ((size_t)b * NB + gbox) * 5;
            float cls = bx[0], cx = bx[1], cy = bx[2], w = bx[3], h = bx[4];
            int ni = nidx[b * NB + gbox] - 3;
            int ix = (int)(cx * 0.0625f);
            int iy = (int)(cy * 0.0625f);
            float ax = (cx - (float)ix * 16.0f) * 0.0625f;
            float ay = (cy - (float)iy * 16.0f) * 0.0625f;
            int cell = ix * S_DIM + iy;
            int off  = ni * CH_BLK * CELLS + cell;
            s_key[tid] = ni * CELLS + cell;
            s_off[tid] = off;
            s_cls[tid] = (int)cls;
            if (slice == 0) s_obj2[tid] = xb[off] * xb[off];
            // head terms: slice0 -> boxes tid<16 == 0..15; slice1 -> tid<16 == 16..31
            if (tid < 16)
                r0 += head_terms(xb, off, ni, w, h, ax, ay);
        }
        __syncthreads();
        if (slice == 0 && tid < NB) {
            // dedupe: distinct-count and obj^2 correction
            bool first = true;
            for (int s = 0; s < tid; ++s)
                if (s_key[s] == s_key[tid]) { first = false; break; }
            if (first) { r2 += 1.0f; r1 += s_obj2[tid]; }
        }
        // ---- label (class) term for this slice's 16 boxes: 1280 scattered loads ----
        #pragma unroll
        for (int u = tid; u < 16 * NCLS; u += 256) {
            int t = u / NCLS;          // local box 0..15
            int c = u - t * NCLS;
            int lt = (slice == 0) ? t : t;  // s_off local index is 0..15 in slice1, 0..15 used in slice0 too
            float val = xb[s_off[lt] + (5 + c) * CELLS];
            float hot = (c == s_cls[lt]) ? 1.0f : 0.0f;
            float d = val - hot;
            r0 += d * d;
        }
        // scale: r0 currently = accA_partial + accL_partial; split scales:
        // head terms need *5/32, labels need /2560. They're mixed — redo:
        // (we kept them mixed; separate below via recompute) -- instead keep separate:
    }

    // NOTE: for slices 0/1 we must scale head vs label differently; we kept head
    // in r0 via head_terms and labels also in r0 — fix by scaling at accumulate
    // time instead. To keep this correct we scaled here:
    // (head_terms was added unscaled; labels unscaled). Separate them:
    // Simplest: we re-scale by tracking head sum in r2 is taken (slice0) — so
    // instead we fold scales directly at add time above. To avoid subtle bugs,
    // the adds above were left unscaled and we now finish with a uniform
    // approach: head contributions came only from tid<16 (r0 includes both).
    // => We instead applied scaling below via a per-thread split flag. See
    // head_scaled/label_scaled computed inline:

    // --- block reduction of r0, r1, r2 ---
    #pragma unroll
    for (int o = 32; o > 0; o >>= 1) {
        r0 += __shfl_down(r0, o, 64);
        r1 += __shfl_down(r1, o, 64);
        r2 += __shfl_down(r2, o, 64);
    }
    int wave = tid >> 6;
    if ((tid & 63) == 0) { s_red[0][wave] = r0; s_red[1][wave] = r1; s_red[2][wave] = r2; }
    __syncthreads();
    if (tid == 0) {
        float t0 = s_red[0][0] + s_red[0][1] + s_red[0][2] + s_red[0][3];
        float t1 = s_red[1][0] + s_red[1][1] + s_red[1][2] + s_red[1][3];
        float t2 = s_red[2][0] + s_red[2][1] + s_red[2][2] + s_red[2][3];
        float contrib;
        if (slice == 2) {
            float cnt = 2028.0f - t1;
            contrib = 0.5f * t0 / cnt;           // + LAMBDA_NOOBJ * plane_sq/cnt
        } else if (slice == 0) {
            float cnt = 2028.0f - t2;
            contrib = t0 - 0.5f * t1 / cnt;      // head+label partial - obj^2 correction
        } else {
            contrib = t0;
        }
        atomicAdd(out, contrib);
    }
}

// Scaling fix: head terms must be *5/32 and labels /2560. We do that by
// pre-scaling inside the loops — wrapper kernel below re-emits with scales
// applied at the accumulation sites (the version above is superseded by
// the scaled adds in this final kernel).

__global__ __launch_bounds__(256)
void yolo_loss_kernel_scaled(const float* __restrict__ x,
                             const float* __restrict__ box,
                             const int*   __restrict__ nidx,
                             float* __restrict__ out)
{
    const int b     = blockIdx.x;
    const int slice = blockIdx.y;
    const int tid   = threadIdx.x;
    const float* xb = x + (size_t)b * (NCH * CELLS);

    __shared__ int   s_key[NB];
    __shared__ int   s_off[NB];
    __shared__ int   s_cls[NB];
    __shared__ float s_obj2[NB];
    __shared__ float s_red[3][4];

    float r0 = 0.f, r1 = 0.f, r2 = 0.f;

    if (slice == 2) {
        if (tid < NB) {
            const float* bx = box + ((size_t)b * NB + tid) * 5;
            float cx = bx[1], cy = bx[2];
            int ni = nidx[b * NB + tid] - 3;
            int ix = (int)(cx * 0.0625f);
            int iy = (int)(cy * 0.0625f);
            s_key[tid] = ni * CELLS + ix * S_DIM + iy;
        }
        __syncthreads();
        if (tid < NB) {
            bool first = true;
            for (int s = 0; s < tid; ++s)
                if (s_key[s] == s_key[tid]) { first = false; break; }
            if (first) r1 += 1.0f;
        }
        const float4* p4 = (const float4*)xb;
        for (int u = tid; u < PLANE_F4; u += 256) {
            int pl = (u >= 2 * F4_PER_PLANE) ? 2 : (u >= F4_PER_PLANE ? 1 : 0);
            int i4 = u - pl * F4_PER_PLANE;
            float4 v = p4[pl * F4_PLANE_STRIDE + i4];
            r0 += v.x * v.x + v.y * v.y + v.z * v.z + v.w * v.w;
        }
    } else {
        const int boxbase = slice * 16;
        const int nmeta = (slice == 0) ? NB : 16;
        if (tid < nmeta) {
            int gbox = (slice == 0) ? tid : (boxbase + tid);
            const float* bx = box + ((size_t)b * NB + gbox) * 5;
            float cls = bx[0], cx = bx[1], cy = bx[2], w = bx[3], h = bx[4];
            int ni = nidx[b * NB + gbox] - 3;
            int ix = (int)(cx * 0.0625f);
            int iy = (int)(cy * 0.0625f);
            float ax = (cx - (float)ix * 16.0f) * 0.0625f;
            float ay = (cy - (float)iy * 16.0f) * 0.0625f;
            int cell = ix * S_DIM + iy;
            int off  = ni * CH_BLK * CELLS + cell;
            s_key[tid] = ni * CELLS + cell;
            s_off[tid] = off;
            s_cls[tid] = (int)cls;
            if (slice == 0) s_obj2[tid] = xb[off] * xb[off];
            bool do_head = (slice == 0) ? (tid < 16) : true;
            if (do_head)
                r0 += head_terms(xb, off, ni, w, h, ax, ay) * (5.0f / 32.0f);
        }
        __syncthreads();
        if (slice == 0 && tid < NB) {
            bool first = true;
            for (int s = 0; s < tid; ++s)
                if (s_key[s] == s_key[tid]) { first = false; break; }
            if (first) { r2 += 1.0f; r1 += s_obj2[tid]; }
        }
        for (int u = tid; u < 16 * NCLS; u += 256) {
            int t = u / NCLS;
            int c = u - t * NCLS;
            float val = xb[s_off[t] + (5 + c) * CELLS];
            float hot = (c == s_cls[t]) ? 1.0f : 0.0f;
            float d = val - hot;
            r0 += d * d * (1.0f / 2560.0f);
        }
    }

    #pragma unroll
    for (int o = 32; o > 0; o >>= 1) {
        r0 += __shfl_down(r0, o, 64);
        r1 += __shfl_down(r1, o, 64);
        r2 += __shfl_down(r2, o, 64);
    }
    int wave = tid >> 6;
    if ((tid & 63) == 0) { s_red[0][wave] = r0; s_red[1][wave] = r1; s_red[2][wave] = r2; }
    __syncthreads();
    if (tid == 0) {
        float t0 = s_red[0][0] + s_red[0][1] + s_red[0][2] + s_red[0][3];
        float t1 = s_red[1][0] + s_red[1][1] + s_red[1][2] + s_red[1][3];
        float t2 = s_red[2][0] + s_red[2][1] + s_red[2][2] + s_red[2][3];
        float contrib;
        if (slice == 2) {
            float cnt = 2028.0f - t1;
            contrib = 0.5f * t0 / cnt;
        } else if (slice == 0) {
            float cnt = 2028.0f - t2;
            contrib = t0 - 0.5f * t1 / cnt;
        } else {
            contrib = t0;
        }
        atomicAdd(out, contrib);
    }
}

extern "C" void kernel_launch(void* const* d_in, const int* in_sizes, int n_in,
                              void* d_out, int out_size, void* d_ws, size_t ws_size,
                              hipStream_t stream) {
    const float* x    = (const float*)d_in[0];
    const float* box  = (const float*)d_in[1];
    const int*   nidx = (const int*)d_in[2];
    float* out = (float*)d_out;

    hipMemsetAsync(out, 0, sizeof(float) * out_size, stream);
    yolo_loss_kernel_scaled<<<dim3(256, 3), dim3(256), 0, stream>>>(x, box, nidx, out);
}